// Round 9
// baseline (156.495 us; speedup 1.0000x reference)
//
#include <hip/hip_runtime.h>
#include <stdint.h>
#include <math.h>

// MultHeadAtten: B=1, S=4096, D=768, H=12, Dk=64.
// Q=K=V projections all use Wq/bq (faithful to reference).
// bf16 MFMA; flash attention with swapped QK^T (S^T = mfma(K,Q)) so P stays
// in-lane for PV. V^T computed directly by swapped-operand GEMM, columns
// bit-permuted (slot convention). NO-max softmax in log2 domain (Q pre-scaled
// by 0.125*log2e). Attn: 4 waves/block, each wave owns a PRIVATE K/V double
// buffer and one KV quarter (1024 rows, KVBLK=32); all waves share the
// block's 64 q-rows. NO barriers in the loop: RAW enforced by counted
// s_waitcnt vmcnt(8) (T3+T4). Row sums via ones-column PV MFMA (oacc[][4]).
// 4-way O combine through LDS at the end.

#define SQ 4096
#define DM 768
#define NH 12

typedef float f32x4 __attribute__((ext_vector_type(4)));
typedef short bf16x8 __attribute__((ext_vector_type(8)));
typedef unsigned int u32x4 __attribute__((ext_vector_type(4)));
typedef unsigned short ushort_t;

static __device__ __forceinline__ ushort_t f2bf(float f) {
    unsigned int u = __builtin_bit_cast(unsigned int, f);
    u += 0x7fffu + ((u >> 16) & 1u);
    return (ushort_t)(u >> 16);
}

// pack 2 f32 -> 2 bf16 in one u32 (lo = a, hi = b), RNE.
static __device__ __forceinline__ unsigned int cvt_pk_bf16(float a, float b) {
    unsigned int d;
    asm("v_cvt_pk_bf16_f32 %0, %1, %2" : "=v"(d) : "v"(a), "v"(b));
    return d;
}

// native HW exp2 (v_exp_f32 computes 2^x): single TRANS instruction.
static __device__ __forceinline__ float exp2_hw(float x) {
    float r;
    asm("v_exp_f32 %0, %1" : "=v"(r) : "v"(x));
    return r;
}

// global -> LDS async 16B/lane. LDS dest is wave-uniform base; HW writes
// lane i at base + 16*i.
static __device__ __forceinline__ void gload16(const ushort_t* g, ushort_t* l) {
    __builtin_amdgcn_global_load_lds(
        reinterpret_cast<const __attribute__((address_space(1))) unsigned int*>(
            reinterpret_cast<uintptr_t>(g)),
        reinterpret_cast<__attribute__((address_space(3))) unsigned int*>(
            reinterpret_cast<uintptr_t>(l)),
        16, 0, 0);
}

#define WAITV8 do { asm volatile("s_waitcnt vmcnt(8)" ::: "memory"); \
                    __builtin_amdgcn_sched_barrier(0); } while (0)
#define WAITV0 do { asm volatile("s_waitcnt vmcnt(0)" ::: "memory"); \
                    __builtin_amdgcn_sched_barrier(0); } while (0)

// One fused convert kernel: q,k,v -> xb (3*NE), Wq -> wqb, Wo -> wob.
__global__ __launch_bounds__(256) void cvt_all(
    const float* __restrict__ q, const float* __restrict__ k,
    const float* __restrict__ v, const float* __restrict__ Wq,
    const float* __restrict__ Wo, ushort_t* __restrict__ xb,
    ushort_t* __restrict__ wqb, ushort_t* __restrict__ wob) {
    const int NE4 = (SQ * DM) / 4;      // 786432
    const int NW4 = (DM * DM) / 4;      // 147456
    int i = blockIdx.x * 256 + threadIdx.x;
    const float* src;
    ushort_t* dst;
    if (i < NE4) { src = q; dst = xb; }
    else if (i < 2 * NE4) { src = k; dst = xb + SQ * DM; i -= NE4; }
    else if (i < 3 * NE4) { src = v; dst = xb + 2 * SQ * DM; i -= 2 * NE4; }
    else if (i < 3 * NE4 + NW4) { src = Wq; dst = wqb; i -= 3 * NE4; }
    else if (i < 3 * NE4 + 2 * NW4) { src = Wo; dst = wob; i -= 3 * NE4 + NW4; }
    else return;
    float4 x = reinterpret_cast<const float4*>(src)[i];
    ushort4 o;
    o.x = f2bf(x.x); o.y = f2bf(x.y); o.z = f2bf(x.z); o.w = f2bf(x.w);
    reinterpret_cast<ushort4*>(dst)[i] = o;
}

// C[M x N] = A[M x 768(K)] * B[N x 768(K)]^T (+ bias), bf16 row-major inputs.
// EPI 0: N=768. rows < 4096 -> Q rows scaled by 0.125*log2e; else K rows.
// EPI 1: N=768. fp32 out row-major, bias by col.
// EPI 2: N=4096 (B=xv, A=Wq). C rows are d (bias by ROW), cols are kv;
//        write vt[d][perm(kv)], perm = bits {b4,b3,b2}->{b3,b2,b4}.
template <int EPI>
__global__ __launch_bounds__(256) void gemm_bf16(
    const ushort_t* __restrict__ A, const ushort_t* __restrict__ B,
    const float* __restrict__ bias, ushort_t* __restrict__ proj,
    ushort_t* __restrict__ vt, float* __restrict__ outf) {
    __shared__ __align__(16) ushort_t lsA[128 * 64];
    __shared__ __align__(16) ushort_t lsB[128 * 64];
    const int tid = threadIdx.x;
    const int lane = tid & 63;
    const int w = tid >> 6;
    const int wm = w >> 1, wn = w & 1;
    const int g = lane >> 4, li = lane & 15;
    const int NB = (EPI == 2) ? 32 : 6;
    const int bm = blockIdx.x / NB, bn = blockIdx.x % NB;
    const int arow = bm * 128, brow = bn * 128;
    const int sr = lane >> 3;
    const int sc = ((lane & 7) ^ sr) * 8;

    f32x4 acc[4][4] = {};

    for (int kt = 0; kt < 12; ++kt) {
        const int k0 = kt * 64;
        __syncthreads();
#pragma unroll
        for (int c = 0; c < 4; ++c) {
            const int chunk = w * 4 + c;
            const int r = chunk * 8 + sr;
            gload16(A + (size_t)(arow + r) * DM + k0 + sc, lsA + chunk * 512);
            gload16(B + (size_t)(brow + r) * DM + k0 + sc, lsB + chunk * 512);
        }
        __syncthreads();

        bf16x8 af[4][2];
#pragma unroll
        for (int mf = 0; mf < 4; ++mf) {
            const int row = wm * 64 + mf * 16 + li;
#pragma unroll
            for (int ks = 0; ks < 2; ++ks)
                af[mf][ks] = *reinterpret_cast<const bf16x8*>(
                    lsA + row * 64 + ((ks * 32 + g * 8) ^ ((li & 7) << 3)));
        }
#pragma unroll
        for (int nf = 0; nf < 4; ++nf) {
            const int row = wn * 64 + nf * 16 + li;
            bf16x8 b0 = *reinterpret_cast<const bf16x8*>(
                lsB + row * 64 + ((g * 8) ^ ((li & 7) << 3)));
            bf16x8 b1 = *reinterpret_cast<const bf16x8*>(
                lsB + row * 64 + ((32 + g * 8) ^ ((li & 7) << 3)));
#pragma unroll
            for (int mf = 0; mf < 4; ++mf) {
                acc[mf][nf] = __builtin_amdgcn_mfma_f32_16x16x32_bf16(af[mf][0], b0, acc[mf][nf], 0, 0, 0);
                acc[mf][nf] = __builtin_amdgcn_mfma_f32_16x16x32_bf16(af[mf][1], b1, acc[mf][nf], 0, 0, 0);
            }
        }
    }

    // Epilogue. C/D layout: col = li, row = g*4 + reg.
    if (EPI == 0) {
        const float qscale = (arow < 4096) ? 0.18033688011112042f : 1.0f;  // 0.125*log2e
#pragma unroll
        for (int nf = 0; nf < 4; ++nf) {
            const int col = brow + wn * 64 + nf * 16 + li;
            const float bv = bias[col];
#pragma unroll
            for (int mf = 0; mf < 4; ++mf) {
                const int row0 = arow + wm * 64 + mf * 16 + g * 4;
#pragma unroll
                for (int r = 0; r < 4; ++r)
                    proj[(size_t)(row0 + r) * DM + col] = f2bf((acc[mf][nf][r] + bv) * qscale);
            }
        }
    } else if (EPI == 2) {
        // rows = d (bias by row), cols = kv -> vt[d][perm(kv)].
        float bv[4][4];
#pragma unroll
        for (int mf = 0; mf < 4; ++mf)
#pragma unroll
            for (int r = 0; r < 4; ++r)
                bv[mf][r] = bias[arow + wm * 64 + mf * 16 + g * 4 + r];
#pragma unroll
        for (int nf = 0; nf < 4; ++nf) {
            const int j = brow + wn * 64 + nf * 16 + li;
            const int pos = (j & ~31) | ((j & 0xC) << 1) | (((j >> 4) & 1) << 2) | (j & 3);
#pragma unroll
            for (int mf = 0; mf < 4; ++mf) {
                const int row0 = arow + wm * 64 + mf * 16 + g * 4;
#pragma unroll
                for (int r = 0; r < 4; ++r)
                    vt[(size_t)(row0 + r) * SQ + pos] = f2bf(acc[mf][nf][r] + bv[mf][r]);
            }
        }
    } else {
#pragma unroll
        for (int nf = 0; nf < 4; ++nf) {
            const int col = brow + wn * 64 + nf * 16 + li;
            const float bv = bias[col];
#pragma unroll
            for (int mf = 0; mf < 4; ++mf) {
                const int row0 = arow + wm * 64 + mf * 16 + g * 4;
#pragma unroll
                for (int r = 0; r < 4; ++r)
                    outf[(size_t)(row0 + r) * DM + col] = acc[mf][nf][r] + bv;
            }
        }
    }
}

// Flash attention: barrier-free wave-private pipeline.
// Grid = 768 blocks (XCD-swizzled), 256 threads = 4 waves.
// Block covers 64 q-rows (all waves share them, qh=4); wave w owns KV
// quarter [w*1024,(w+1)*1024), KVBLK=32, private double buffer (16KB/wave).
// Counted vmcnt(8) replaces barriers. Row sums via ones-MFMA (oacc[qh][4]).
// qk: [8192][768] bf16 (rows 0..4095 = Q pre-scaled, 4096..8191 = K).
// vtb: [768][4096] bf16, columns permuted per slot convention.
// cc: [4096][768] bf16.
__global__ __launch_bounds__(256) void attn_bf16(
    const ushort_t* __restrict__ qk, const ushort_t* __restrict__ vtb,
    ushort_t* __restrict__ cc) {
    __shared__ __align__(16) ushort_t smem[32768];  // 64KB

    const int tid = threadIdx.x, lane = tid & 63, w = tid >> 6;  // w 0..3
    const int g = lane >> 4, li = lane & 15;
    // XCD swizzle: 768 = 8 * 96; head-major logical order.
    const int logical = (blockIdx.x & 7) * 96 + (blockIdx.x >> 3);
    const int h = logical >> 6, qb = logical & 63;
    // K staging: 1KB chunks of 8 rows x 128B; source col pre-swizzled.
    const int sr = lane >> 3;
    const int sc = ((lane & 7) ^ sr) * 8;
    // V staging: 1KB chunks of 16 d-rows x 64B; slot swizzle f(d)=(d>>1)&3.
    const int vdr = lane >> 2;
    const int vsc = ((lane & 3) ^ ((lane >> 3) & 3)) * 8;

    const ushort_t* Kb = qk + (size_t)(4096 + w * 1024) * DM + (size_t)h * 64;
    const ushort_t* Vb = vtb + (size_t)(h * 64) * SQ + w * 1024;

    // Wave-private buffers: [K0 2048][V0 2048][K1 2048][V1 2048] ushorts.
    ushort_t* K0 = smem + w * 8192;
    ushort_t* V0 = K0 + 2048;
    ushort_t* K1 = K0 + 4096;
    ushort_t* V1 = K0 + 6144;

    // Q fragments: 64 q-rows shared by all waves (qh = 0..3).
    bf16x8 qf[4][2];
#pragma unroll
    for (int qh = 0; qh < 4; ++qh)
#pragma unroll
        for (int ks = 0; ks < 2; ++ks)
            qf[qh][ks] = *reinterpret_cast<const bf16x8*>(
                qk + (size_t)(qb * 64 + qh * 16 + li) * DM + h * 64 + ks * 32 + g * 8);

    f32x4 oacc[4][5] = {};  // [qh][nv]; nv=4 = row-sum via ones-MFMA

    const unsigned int one2 = 0x3F803F80u;  // 2 x bf16 1.0
    u32x4 onesu = {one2, one2, one2, one2};
    const bf16x8 vones = __builtin_bit_cast(bf16x8, onesu);

    WAITV0;  // drain qf loads so loop vmcnt counts are exact

    // Prologue: stage tile 0 into buf 0 (8 wave-wide loads).
#pragma unroll
    for (int c = 0; c < 4; ++c) {
        gload16(Kb + (size_t)(c * 8 + sr) * DM + sc, K0 + c * 512);
        gload16(Vb + (size_t)(c * 16 + vdr) * SQ + vsc, V0 + c * 512);
    }

    // One KV step. Stage tile `nxt` into kn/vn (if DOSTAGE), wait for the
    // current tile's 8 loads (vmcnt(8): only the 8 just-issued outstanding),
    // compute from kp/vp. No barriers: buffers are wave-private.
#define STEP(kp, vp, kn, vn, nxt, DOSTAGE)                                     \
    do {                                                                       \
        if (DOSTAGE) {                                                         \
            const int kvo = (nxt) * 32;                                        \
            _Pragma("unroll") for (int c = 0; c < 4; ++c) {                    \
                gload16(Kb + (size_t)(kvo + c * 8 + sr) * DM + sc,             \
                        (kn) + c * 512);                                       \
                gload16(Vb + (size_t)(c * 16 + vdr) * SQ + kvo + vsc,          \
                        (vn) + c * 512);                                       \
            }                                                                  \
            WAITV8;                                                            \
        } else {                                                               \
            WAITV0;                                                            \
        }                                                                      \
        f32x4 sf[4][2];                                                        \
        _Pragma("unroll") for (int qh = 0; qh < 4; ++qh)                       \
            _Pragma("unroll") for (int nf = 0; nf < 2; ++nf)                   \
                sf[qh][nf] = (f32x4){0.f, 0.f, 0.f, 0.f};                      \
        __builtin_amdgcn_s_setprio(1);                                         \
        _Pragma("unroll") for (int nf = 0; nf < 2; ++nf) {                     \
            const int row = nf * 16 + li;                                      \
            bf16x8 kb0 = *reinterpret_cast<const bf16x8*>(                     \
                (kp) + row * 64 + ((g * 8) ^ ((li & 7) << 3)));                \
            bf16x8 kb1 = *reinterpret_cast<const bf16x8*>(                     \
                (kp) + row * 64 + ((32 + g * 8) ^ ((li & 7) << 3)));           \
            _Pragma("unroll") for (int qh = 0; qh < 4; ++qh) {                 \
                sf[qh][nf] = __builtin_amdgcn_mfma_f32_16x16x32_bf16(          \
                    kb0, qf[qh][0], sf[qh][nf], 0, 0, 0);                      \
                sf[qh][nf] = __builtin_amdgcn_mfma_f32_16x16x32_bf16(          \
                    kb1, qf[qh][1], sf[qh][nf], 0, 0, 0);                      \
            }                                                                  \
        }                                                                      \
        __builtin_amdgcn_s_setprio(0);                                         \
        bf16x8 pa[4];                                                          \
        _Pragma("unroll") for (int qh = 0; qh < 4; ++qh) {                     \
            f32x4 p0, p1;                                                      \
            _Pragma("unroll") for (int r = 0; r < 4; ++r) {                    \
                p0[r] = exp2_hw(sf[qh][0][r]);                                 \
                p1[r] = exp2_hw(sf[qh][1][r]);                                 \
            }                                                                  \
            u32x4 pu;                                                          \
            pu.x = cvt_pk_bf16(p0[0], p0[1]);                                  \
            pu.y = cvt_pk_bf16(p0[2], p0[3]);                                  \
            pu.z = cvt_pk_bf16(p1[0], p1[1]);                                  \
            pu.w = cvt_pk_bf16(p1[2], p1[3]);                                  \
            pa[qh] = __builtin_bit_cast(bf16x8, pu);                           \
        }                                                                      \
        __builtin_amdgcn_s_setprio(1);                                         \
        _Pragma("unroll") for (int nv = 0; nv < 4; ++nv) {                     \
            const int vrow = nv * 16 + li;                                     \
            bf16x8 vb = *reinterpret_cast<const bf16x8*>(                      \
                (vp) + vrow * 32 + ((g ^ ((li >> 1) & 3)) * 8));               \
            _Pragma("unroll") for (int qh = 0; qh < 4; ++qh)                   \
                oacc[qh][nv] = __builtin_amdgcn_mfma_f32_16x16x32_bf16(        \
                    pa[qh], vb, oacc[qh][nv], 0, 0, 0);                        \
        }                                                                      \
        _Pragma("unroll") for (int qh = 0; qh < 4; ++qh)                       \
            oacc[qh][4] = __builtin_amdgcn_mfma_f32_16x16x32_bf16(             \
                pa[qh], vones, oacc[qh][4], 0, 0, 0);                          \
        __builtin_amdgcn_s_setprio(0);                                         \
    } while (0)

#pragma unroll 1
    for (int t = 0; t < 15; ++t) {
        STEP(K0, V0, K1, V1, 2 * t + 1, true);
        STEP(K1, V1, K0, V0, 2 * t + 2, true);
    }
    STEP(K0, V0, K1, V1, 31, true);   // tile 30, stage 31
    STEP(K1, V1, K0, V0, 32, false);  // tile 31, drain
#undef STEP

    // 4-way combine across waves (exact: no-max softmax). Reuse smem.
    __syncthreads();
    float* ob = reinterpret_cast<float*>(smem);
    if (w > 0) {
        float* base = ob + (w - 1) * 5120;  // 20KB per wave
#pragma unroll
        for (int qh = 0; qh < 4; ++qh)
#pragma unroll
            for (int nv = 0; nv < 5; ++nv)
                *reinterpret_cast<f32x4*>(
                    base + ((qh * 5 + nv) * 64 + lane) * 4) = oacc[qh][nv];
    }
    __syncthreads();
    if (w == 0) {
#pragma unroll
        for (int j = 0; j < 3; ++j) {
            const float* base = ob + j * 5120;
#pragma unroll
            for (int qh = 0; qh < 4; ++qh)
#pragma unroll
                for (int nv = 0; nv < 5; ++nv)
                    oacc[qh][nv] += *reinterpret_cast<const f32x4*>(
                        base + ((qh * 5 + nv) * 64 + lane) * 4);
        }
        // Row sum for q = qh*16 + g*4 + r sits in oacc[qh][4][r] (all li).
#pragma unroll
        for (int qh = 0; qh < 4; ++qh) {
            float inv[4];
#pragma unroll
            for (int r = 0; r < 4; ++r) inv[r] = 1.0f / oacc[qh][4][r];
#pragma unroll
            for (int nv = 0; nv < 4; ++nv)
#pragma unroll
                for (int r = 0; r < 4; ++r) {
                    const int row = qb * 64 + qh * 16 + g * 4 + r;
                    const int col = h * 64 + nv * 16 + li;
                    cc[(size_t)row * DM + col] = f2bf(oacc[qh][nv][r] * inv[r]);
                }
        }
    }
}

extern "C" void kernel_launch(void* const* d_in, const int* in_sizes, int n_in,
                              void* d_out, int out_size, void* d_ws, size_t ws_size,
                              hipStream_t stream) {
    const float* q = (const float*)d_in[0];
    const float* k = (const float*)d_in[1];
    const float* v = (const float*)d_in[2];
    const float* Wq = (const float*)d_in[3];
    const float* bq = (const float*)d_in[4];
    const float* Wo = (const float*)d_in[5];
    const float* bo = (const float*)d_in[6];
    float* out = (float*)d_out;

    ushort_t* ws = (ushort_t*)d_ws;
    const int NE = SQ * DM;              // 3145728
    ushort_t* xb = ws;                   // [3*4096][768] bf16 of q,k,v
    ushort_t* wqb = ws + 3 * NE;         // [768][768]
    ushort_t* wob = wqb + DM * DM;       // [768][768]
    ushort_t* proj = wob + DM * DM;      // [8192][768]  Q rows 0.., K rows 4096..
    ushort_t* vt = proj + 2 * NE;        // [768][4096]  V^T, columns permuted
    ushort_t* cc = vt + NE;              // [4096][768]  attention concat

    // Fused converts: 3*NE/4 + 2*DM*DM/4 float4s.
    const int n4 = 3 * (NE / 4) + 2 * ((DM * DM) / 4);
    cvt_all<<<(n4 + 255) / 256, 256, 0, stream>>>(q, k, v, Wq, Wo, xb, wqb, wob);

    // Q/K projection: M = 8192 stacked rows.
    gemm_bf16<0><<<(8192 / 128) * 6, 256, 0, stream>>>(xb, wqb, bq, proj, (ushort_t*)nullptr, (float*)nullptr);

    // V^T projection: A = Wq (M=768), B = xv (N=4096) -> vt [768][4096].
    gemm_bf16<2><<<(768 / 128) * 32, 256, 0, stream>>>(wqb, xb + 2 * NE, bq, (ushort_t*)nullptr, vt, (float*)nullptr);

    // Attention: 768 blocks, 256 threads (4 waves, wave-private KV quarters).
    attn_bf16<<<NH * (SQ / 64), 256, 0, stream>>>(proj, vt, cc);

    // Output projection: M = 4096, fp32 out.
    gemm_bf16<1><<<(SQ / 128) * 6, 256, 0, stream>>>(cc, wob, bo, (ushort_t*)nullptr, (ushort_t*)nullptr, out);
}

// Round 11
// 140.478 us; speedup vs baseline: 1.1140x; 1.1140x over previous
//
#include <hip/hip_runtime.h>
#include <stdint.h>
#include <math.h>

// MultHeadAtten: B=1, S=4096, D=768, H=12, Dk=64.
// Q=K=V projections all use Wq/bq (faithful to reference).
// bf16 MFMA; flash attention with swapped QK^T (S^T = mfma(K,Q)) so P stays
// in-lane for PV. V^T computed directly by swapped-operand GEMM; columns get
// a light XOR (pos = kv ^ (((d>>2)&1)<<3)) purely for LDS bank spreading.
// NO-max softmax in log2 domain (Q pre-scaled by 0.125*log2e).
// Attn: 4 waves/block share 64 q-rows; wave w owns KV quarter (1024 rows),
// KVBLK=16, wave-private TRIPLE-buffered units (12KB/wave, 48KB/block ->
// 3 blocks/CU). Barrier-free pair schedule:
//   even step: stage e+2 at START; vmcnt(8); QK+exp; pack A-half.
//   odd step:  vmcnt(4); QK+exp; pack; PV(V[e],V[e+1]); lgkmcnt(0);
//              stage e+3 at END (into V[e]'s unit -- now provably dead).
// Row sums via ones-column MFMA. 3-step LDS tree combine at end.

#define SQ 4096
#define DM 768
#define NH 12

typedef float f32x4 __attribute__((ext_vector_type(4)));
typedef short bf16x8 __attribute__((ext_vector_type(8)));
typedef unsigned int u32x4 __attribute__((ext_vector_type(4)));
typedef unsigned int u32x2 __attribute__((ext_vector_type(2)));
typedef unsigned short ushort_t;

#define MFMA32(a, b, c) __builtin_amdgcn_mfma_f32_16x16x32_bf16((a), (b), (c), 0, 0, 0)

static __device__ __forceinline__ ushort_t f2bf(float f) {
    unsigned int u = __builtin_bit_cast(unsigned int, f);
    u += 0x7fffu + ((u >> 16) & 1u);
    return (ushort_t)(u >> 16);
}

static __device__ __forceinline__ unsigned int cvt_pk_bf16(float a, float b) {
    unsigned int d;
    asm("v_cvt_pk_bf16_f32 %0, %1, %2" : "=v"(d) : "v"(a), "v"(b));
    return d;
}

static __device__ __forceinline__ float exp2_hw(float x) {
    float r;
    asm("v_exp_f32 %0, %1" : "=v"(r) : "v"(x));
    return r;
}

static __device__ __forceinline__ void gload16(const ushort_t* g, ushort_t* l) {
    __builtin_amdgcn_global_load_lds(
        reinterpret_cast<const __attribute__((address_space(1))) unsigned int*>(
            reinterpret_cast<uintptr_t>(g)),
        reinterpret_cast<__attribute__((address_space(3))) unsigned int*>(
            reinterpret_cast<uintptr_t>(l)),
        16, 0, 0);
}

#define WAITV8 do { asm volatile("s_waitcnt vmcnt(8)" ::: "memory"); \
                    __builtin_amdgcn_sched_barrier(0); } while (0)
#define WAITV4 do { asm volatile("s_waitcnt vmcnt(4)" ::: "memory"); \
                    __builtin_amdgcn_sched_barrier(0); } while (0)
#define WAITV0 do { asm volatile("s_waitcnt vmcnt(0)" ::: "memory"); \
                    __builtin_amdgcn_sched_barrier(0); } while (0)
#define WAITLGKM0 do { asm volatile("s_waitcnt lgkmcnt(0)" ::: "memory"); \
                       __builtin_amdgcn_sched_barrier(0); } while (0)

// One fused convert kernel: q,k,v -> xb (3*NE), Wq -> wqb, Wo -> wob.
__global__ __launch_bounds__(256) void cvt_all(
    const float* __restrict__ q, const float* __restrict__ k,
    const float* __restrict__ v, const float* __restrict__ Wq,
    const float* __restrict__ Wo, ushort_t* __restrict__ xb,
    ushort_t* __restrict__ wqb, ushort_t* __restrict__ wob) {
    const int NE4 = (SQ * DM) / 4;
    const int NW4 = (DM * DM) / 4;
    int i = blockIdx.x * 256 + threadIdx.x;
    const float* src;
    ushort_t* dst;
    if (i < NE4) { src = q; dst = xb; }
    else if (i < 2 * NE4) { src = k; dst = xb + SQ * DM; i -= NE4; }
    else if (i < 3 * NE4) { src = v; dst = xb + 2 * SQ * DM; i -= 2 * NE4; }
    else if (i < 3 * NE4 + NW4) { src = Wq; dst = wqb; i -= 3 * NE4; }
    else if (i < 3 * NE4 + 2 * NW4) { src = Wo; dst = wob; i -= 3 * NE4 + NW4; }
    else return;
    float4 x = reinterpret_cast<const float4*>(src)[i];
    ushort4 o;
    o.x = f2bf(x.x); o.y = f2bf(x.y); o.z = f2bf(x.z); o.w = f2bf(x.w);
    reinterpret_cast<ushort4*>(dst)[i] = o;
}

// Fused QK-projection + V^T-projection, one launch (576 blocks).
// Blocks 0..383:  C = xb[0..8192) * Wq^T + bq -> proj (Q rows scaled).
// Blocks 384..575: C = Wq * xv^T + bq(row) -> vt[d][kv ^ (((d>>2)&1)<<3)].
__global__ __launch_bounds__(256) void gemm_qkv(
    const ushort_t* __restrict__ xb, const ushort_t* __restrict__ wqb,
    const float* __restrict__ bq, ushort_t* __restrict__ proj,
    ushort_t* __restrict__ vt) {
    __shared__ __align__(16) ushort_t lsA[128 * 64];
    __shared__ __align__(16) ushort_t lsB[128 * 64];
    const int tid = threadIdx.x;
    const int lane = tid & 63;
    const int w = tid >> 6;
    const int wm = w >> 1, wn = w & 1;
    const int g = lane >> 4, li = lane & 15;
    const bool isV = blockIdx.x >= 384;
    const ushort_t* A;
    const ushort_t* B;
    int bm, bn;
    if (!isV) {
        A = xb; B = wqb;
        bm = blockIdx.x / 6; bn = blockIdx.x % 6;
    } else {
        A = wqb; B = xb + 2 * SQ * DM;
        const int b2 = blockIdx.x - 384;
        bm = b2 / 32; bn = b2 % 32;
    }
    const int arow = bm * 128, brow = bn * 128;
    const int sr = lane >> 3;
    const int sc = ((lane & 7) ^ sr) * 8;

    f32x4 acc[4][4] = {};

    for (int kt = 0; kt < 12; ++kt) {
        const int k0 = kt * 64;
        __syncthreads();
#pragma unroll
        for (int c = 0; c < 4; ++c) {
            const int chunk = w * 4 + c;
            const int r = chunk * 8 + sr;
            gload16(A + (size_t)(arow + r) * DM + k0 + sc, lsA + chunk * 512);
            gload16(B + (size_t)(brow + r) * DM + k0 + sc, lsB + chunk * 512);
        }
        __syncthreads();

        bf16x8 af[4][2];
#pragma unroll
        for (int mf = 0; mf < 4; ++mf) {
            const int row = wm * 64 + mf * 16 + li;
#pragma unroll
            for (int ks = 0; ks < 2; ++ks)
                af[mf][ks] = *reinterpret_cast<const bf16x8*>(
                    lsA + row * 64 + ((ks * 32 + g * 8) ^ ((li & 7) << 3)));
        }
#pragma unroll
        for (int nf = 0; nf < 4; ++nf) {
            const int row = wn * 64 + nf * 16 + li;
            bf16x8 b0 = *reinterpret_cast<const bf16x8*>(
                lsB + row * 64 + ((g * 8) ^ ((li & 7) << 3)));
            bf16x8 b1 = *reinterpret_cast<const bf16x8*>(
                lsB + row * 64 + ((32 + g * 8) ^ ((li & 7) << 3)));
#pragma unroll
            for (int mf = 0; mf < 4; ++mf) {
                acc[mf][nf] = MFMA32(af[mf][0], b0, acc[mf][nf]);
                acc[mf][nf] = MFMA32(af[mf][1], b1, acc[mf][nf]);
            }
        }
    }

    // C/D layout: col = li, row = g*4 + reg.
    if (!isV) {
        const float qscale = (arow < 4096) ? 0.18033688011112042f : 1.0f;  // 0.125*log2e
#pragma unroll
        for (int nf = 0; nf < 4; ++nf) {
            const int col = brow + wn * 64 + nf * 16 + li;
            const float bv = bq[col];
#pragma unroll
            for (int mf = 0; mf < 4; ++mf) {
                const int row0 = arow + wm * 64 + mf * 16 + g * 4;
#pragma unroll
                for (int r = 0; r < 4; ++r)
                    proj[(size_t)(row0 + r) * DM + col] = f2bf((acc[mf][nf][r] + bv) * qscale);
            }
        }
    } else {
        // rows = d (bias by row), cols = kv; pos = kv ^ (((d>>2)&1)<<3).
        // (d>>2)&1 == g&1 here (row0 = ..multiple of 16.. + g*4).
        float bv[4][4];
#pragma unroll
        for (int mf = 0; mf < 4; ++mf)
#pragma unroll
            for (int r = 0; r < 4; ++r)
                bv[mf][r] = bq[arow + wm * 64 + mf * 16 + g * 4 + r];
        const int xg = (g & 1) << 3;
#pragma unroll
        for (int nf = 0; nf < 4; ++nf) {
            const int j = brow + wn * 64 + nf * 16 + li;
            const int pos = j ^ xg;
#pragma unroll
            for (int mf = 0; mf < 4; ++mf) {
                const int row0 = arow + wm * 64 + mf * 16 + g * 4;
#pragma unroll
                for (int r = 0; r < 4; ++r)
                    vt[(size_t)(row0 + r) * SQ + pos] = f2bf(acc[mf][nf][r] + bv[mf][r]);
            }
        }
    }
}

// Output projection: out[4096][768] fp32 = cc * Wo^T + bo.
__global__ __launch_bounds__(256) void gemm_out(
    const ushort_t* __restrict__ cc, const ushort_t* __restrict__ wob,
    const float* __restrict__ bo, float* __restrict__ outf) {
    __shared__ __align__(16) ushort_t lsA[128 * 64];
    __shared__ __align__(16) ushort_t lsB[128 * 64];
    const int tid = threadIdx.x;
    const int lane = tid & 63;
    const int w = tid >> 6;
    const int wm = w >> 1, wn = w & 1;
    const int g = lane >> 4, li = lane & 15;
    const int bm = blockIdx.x / 6, bn = blockIdx.x % 6;
    const int arow = bm * 128, brow = bn * 128;
    const int sr = lane >> 3;
    const int sc = ((lane & 7) ^ sr) * 8;

    f32x4 acc[4][4] = {};

    for (int kt = 0; kt < 12; ++kt) {
        const int k0 = kt * 64;
        __syncthreads();
#pragma unroll
        for (int c = 0; c < 4; ++c) {
            const int chunk = w * 4 + c;
            const int r = chunk * 8 + sr;
            gload16(cc + (size_t)(arow + r) * DM + k0 + sc, lsA + chunk * 512);
            gload16(wob + (size_t)(brow + r) * DM + k0 + sc, lsB + chunk * 512);
        }
        __syncthreads();

        bf16x8 af[4][2];
#pragma unroll
        for (int mf = 0; mf < 4; ++mf) {
            const int row = wm * 64 + mf * 16 + li;
#pragma unroll
            for (int ks = 0; ks < 2; ++ks)
                af[mf][ks] = *reinterpret_cast<const bf16x8*>(
                    lsA + row * 64 + ((ks * 32 + g * 8) ^ ((li & 7) << 3)));
        }
#pragma unroll
        for (int nf = 0; nf < 4; ++nf) {
            const int row = wn * 64 + nf * 16 + li;
            bf16x8 b0 = *reinterpret_cast<const bf16x8*>(
                lsB + row * 64 + ((g * 8) ^ ((li & 7) << 3)));
            bf16x8 b1 = *reinterpret_cast<const bf16x8*>(
                lsB + row * 64 + ((32 + g * 8) ^ ((li & 7) << 3)));
#pragma unroll
            for (int mf = 0; mf < 4; ++mf) {
                acc[mf][nf] = MFMA32(af[mf][0], b0, acc[mf][nf]);
                acc[mf][nf] = MFMA32(af[mf][1], b1, acc[mf][nf]);
            }
        }
    }

#pragma unroll
    for (int nf = 0; nf < 4; ++nf) {
        const int col = brow + wn * 64 + nf * 16 + li;
        const float bv = bo[col];
#pragma unroll
        for (int mf = 0; mf < 4; ++mf) {
            const int row0 = arow + wm * 64 + mf * 16 + g * 4;
#pragma unroll
            for (int r = 0; r < 4; ++r)
                outf[(size_t)(row0 + r) * DM + col] = acc[mf][nf][r] + bv;
        }
    }
}

// Flash attention: barrier-free wave-private triple-buffered pipeline.
__global__ __launch_bounds__(256, 3) void attn_bf16(
    const ushort_t* __restrict__ qk, const ushort_t* __restrict__ vtb,
    ushort_t* __restrict__ cc) {
    __shared__ __align__(16) ushort_t smem[24576];  // 48KB

    const int tid = threadIdx.x, lane = tid & 63, w = tid >> 6;
    const int g = lane >> 4, li = lane & 15;
    const int logical = (blockIdx.x & 7) * 96 + (blockIdx.x >> 3);
    const int h = logical >> 6, qb = logical & 63;
    // K staging: 2 chunks of 8 rows x 128B, XOR-swizzled source cols.
    const int sr = lane >> 3;
    const int sc = ((lane & 7) ^ sr) * 8;
    // V staging: 2 chunks of 32 d-rows x 32B (linear; perm lives in global).
    const int vd = lane >> 1, vh = lane & 1;

    const ushort_t* Kb = qk + (size_t)(4096 + w * 1024) * DM + (size_t)h * 64;
    const ushort_t* Vb = vtb + (size_t)(h * 64) * SQ + w * 1024;

    ushort_t* base = smem + w * 6144;  // 12KB per wave
    ushort_t* K0 = base;          ushort_t* V0 = base + 1024;
    ushort_t* K1 = base + 2048;   ushort_t* V1 = base + 3072;
    ushort_t* K2 = base + 4096;   ushort_t* V2 = base + 5120;

    // LDS read offsets (elems).
    const int ko0 = li * 64 + ((g * 8) ^ ((li & 7) << 3));
    const int ko1 = li * 64 + ((32 + g * 8) ^ ((li & 7) << 3));
    const int vo = li * 16 + 4 * (g ^ (((li >> 2) & 1) << 1));

    // Q fragments: 64 q-rows shared by all waves.
    bf16x8 qf[4][2];
#pragma unroll
    for (int qh = 0; qh < 4; ++qh)
#pragma unroll
        for (int ks = 0; ks < 2; ++ks)
            qf[qh][ks] = *reinterpret_cast<const bf16x8*>(
                qk + (size_t)(qb * 64 + qh * 16 + li) * DM + h * 64 + ks * 32 + g * 8);

    f32x4 oacc[4][5] = {};  // [qh][nv]; nv=4 = row-sum via ones-MFMA
    u32x2 paA[4];

    const unsigned int one2 = 0x3F803F80u;
    u32x4 onesu = {one2, one2, one2, one2};
    const bf16x8 vones = __builtin_bit_cast(bf16x8, onesu);

    auto stage = [&](ushort_t* KT, ushort_t* VT, int kvo) {
        gload16(Kb + (size_t)(kvo + sr) * DM + sc, KT);
        gload16(Kb + (size_t)(kvo + 8 + sr) * DM + sc, KT + 512);
        gload16(Vb + (size_t)vd * SQ + kvo + vh * 8, VT);
        gload16(Vb + (size_t)(32 + vd) * SQ + kvo + vh * 8, VT + 512);
    };

    auto qkexp = [&](const ushort_t* KT, f32x4* P) {
        bf16x8 kb0 = *reinterpret_cast<const bf16x8*>(KT + ko0);
        bf16x8 kb1 = *reinterpret_cast<const bf16x8*>(KT + ko1);
        __builtin_amdgcn_s_setprio(1);
#pragma unroll
        for (int qh = 0; qh < 4; ++qh) {
            f32x4 s = {};
            s = MFMA32(kb0, qf[qh][0], s);
            s = MFMA32(kb1, qf[qh][1], s);
            P[qh] = s;
        }
        __builtin_amdgcn_s_setprio(0);
#pragma unroll
        for (int qh = 0; qh < 4; ++qh) {
            f32x4 p;
#pragma unroll
            for (int r = 0; r < 4; ++r) p[r] = exp2_hw(P[qh][r]);
            P[qh] = p;
        }
    };

    auto pvacc = [&](const ushort_t* VA, const ushort_t* VB, const bf16x8* pa) {
        __builtin_amdgcn_s_setprio(1);
#pragma unroll
        for (int nv = 0; nv < 4; ++nv) {
            short4 a4 = *reinterpret_cast<const short4*>(VA + vo + nv * 256);
            short4 b4 = *reinterpret_cast<const short4*>(VB + vo + nv * 256);
            bf16x8 vb = {a4.x, a4.y, a4.z, a4.w, b4.x, b4.y, b4.z, b4.w};
#pragma unroll
            for (int qh = 0; qh < 4; ++qh)
                oacc[qh][nv] = MFMA32(pa[qh], vb, oacc[qh][nv]);
        }
#pragma unroll
        for (int qh = 0; qh < 4; ++qh)
            oacc[qh][4] = MFMA32(pa[qh], vones, oacc[qh][4]);
        __builtin_amdgcn_s_setprio(0);
    };

    auto packA = [&](const f32x4* P) {
#pragma unroll
        for (int qh = 0; qh < 4; ++qh) {
            u32x2 u;
            u.x = cvt_pk_bf16(P[qh][0], P[qh][1]);
            u.y = cvt_pk_bf16(P[qh][2], P[qh][3]);
            paA[qh] = u;
        }
    };

    auto packO = [&](const f32x4* P, bf16x8* pa) {
#pragma unroll
        for (int qh = 0; qh < 4; ++qh) {
            u32x4 pu;
            pu.x = paA[qh].x;
            pu.y = paA[qh].y;
            pu.z = cvt_pk_bf16(P[qh][0], P[qh][1]);
            pu.w = cvt_pk_bf16(P[qh][2], P[qh][3]);
            pa[qh] = __builtin_bit_cast(bf16x8, pu);
        }
    };

    // One pair of tiles (e even): see header comment for the hazard-free
    // stage placement. KS1/VS1 = unit of tile e+2; KS2/VS2 = unit of e+3
    // (== VE's unit, staged only after lgkmcnt(0) drains the pvacc reads).
    auto pair_full = [&](ushort_t* KE, ushort_t* VE, ushort_t* KO, ushort_t* VO,
                         ushort_t* KS1, ushort_t* VS1, ushort_t* KS2,
                         ushort_t* VS2, int e) {
        stage(KS1, VS1, (e + 2) * 16);
        WAITV8;
        f32x4 P[4];
        qkexp(KE, P);
        packA(P);
        WAITV4;
        f32x4 P2[4];
        qkexp(KO, P2);
        bf16x8 pa[4];
        packO(P2, pa);
        pvacc(VE, VO, pa);
        WAITLGKM0;
        stage(KS2, VS2, (e + 3) * 16);
    };

    WAITV0;  // drain qf loads so vmcnt counts below are exact
    stage(K0, V0, 0);
    stage(K1, V1, 16);

#pragma unroll 1
    for (int i = 0; i < 10; ++i) {
        const int e = i * 6;
        pair_full(K0, V0, K1, V1, K2, V2, K0, V0, e);
        pair_full(K2, V2, K0, V0, K1, V1, K2, V2, e + 2);
        pair_full(K1, V1, K2, V2, K0, V0, K1, V1, e + 4);
    }
    pair_full(K0, V0, K1, V1, K2, V2, K0, V0, 60);  // tiles 60,61; stage 62,63
    {   // final pair: tiles 62 (u2), 63 (u0), no stages
        WAITV4;
        f32x4 P[4];
        qkexp(K2, P);
        packA(P);
        WAITV0;
        f32x4 P2[4];
        qkexp(K0, P2);
        bf16x8 pa[4];
        packO(P2, pa);
        pvacc(V2, V0, pa);
    }

    // 4-way combine (exact: no-max softmax). LDS tree: (2,3)->(0,1)->0.
    __syncthreads();
    float* ob = reinterpret_cast<float*>(smem);
    if (w >= 2) {
        float* bse = ob + (w - 2) * 5120;
#pragma unroll
        for (int qh = 0; qh < 4; ++qh)
#pragma unroll
            for (int nv = 0; nv < 5; ++nv)
                *reinterpret_cast<f32x4*>(
                    bse + ((qh * 5 + nv) * 64 + lane) * 4) = oacc[qh][nv];
    }
    __syncthreads();
    if (w < 2) {
        const float* bse = ob + w * 5120;
#pragma unroll
        for (int qh = 0; qh < 4; ++qh)
#pragma unroll
            for (int nv = 0; nv < 5; ++nv)
                oacc[qh][nv] += *reinterpret_cast<const f32x4*>(
                    bse + ((qh * 5 + nv) * 64 + lane) * 4);
    }
    __syncthreads();
    if (w == 1) {
#pragma unroll
        for (int qh = 0; qh < 4; ++qh)
#pragma unroll
            for (int nv = 0; nv < 5; ++nv)
                *reinterpret_cast<f32x4*>(
                    ob + ((qh * 5 + nv) * 64 + lane) * 4) = oacc[qh][nv];
    }
    __syncthreads();
    if (w == 0) {
#pragma unroll
        for (int qh = 0; qh < 4; ++qh)
#pragma unroll
            for (int nv = 0; nv < 5; ++nv)
                oacc[qh][nv] += *reinterpret_cast<const f32x4*>(
                    ob + ((qh * 5 + nv) * 64 + lane) * 4);
        // Row sum for q = qh*16 + g*4 + r sits in oacc[qh][4][r].
#pragma unroll
        for (int qh = 0; qh < 4; ++qh) {
            float inv[4];
#pragma unroll
            for (int r = 0; r < 4; ++r) inv[r] = 1.0f / oacc[qh][4][r];
#pragma unroll
            for (int nv = 0; nv < 4; ++nv)
#pragma unroll
                for (int r = 0; r < 4; ++r) {
                    const int row = qb * 64 + qh * 16 + g * 4 + r;
                    const int col = h * 64 + nv * 16 + li;
                    cc[(size_t)row * DM + col] = f2bf(oacc[qh][nv][r] * inv[r]);
                }
        }
    }
}

extern "C" void kernel_launch(void* const* d_in, const int* in_sizes, int n_in,
                              void* d_out, int out_size, void* d_ws, size_t ws_size,
                              hipStream_t stream) {
    const float* q = (const float*)d_in[0];
    const float* k = (const float*)d_in[1];
    const float* v = (const float*)d_in[2];
    const float* Wq = (const float*)d_in[3];
    const float* bq = (const float*)d_in[4];
    const float* Wo = (const float*)d_in[5];
    const float* bo = (const float*)d_in[6];
    float* out = (float*)d_out;

    ushort_t* ws = (ushort_t*)d_ws;
    const int NE = SQ * DM;              // 3145728
    ushort_t* xb = ws;                   // [3*4096][768] bf16 of q,k,v
    ushort_t* wqb = ws + 3 * NE;         // [768][768]
    ushort_t* wob = wqb + DM * DM;       // [768][768]
    ushort_t* proj = wob + DM * DM;      // [8192][768]  Q rows 0.., K rows 4096..
    ushort_t* vt = proj + 2 * NE;        // [768][4096]  V^T (bank-XOR columns)
    ushort_t* cc = vt + NE;              // [4096][768]  attention concat

    const int n4 = 3 * (NE / 4) + 2 * ((DM * DM) / 4);
    cvt_all<<<(n4 + 255) / 256, 256, 0, stream>>>(q, k, v, Wq, Wo, xb, wqb, wob);

    // Fused Q/K projection (384 blocks) + V^T projection (192 blocks).
    gemm_qkv<<<576, 256, 0, stream>>>(xb, wqb, bq, proj, vt);

    // Attention: 768 blocks, 256 threads.
    attn_bf16<<<NH * (SQ / 64), 256, 0, stream>>>(proj, vt, cc);

    // Output projection: M = 4096, fp32 out.
    gemm_out<<<(SQ / 128) * 6, 256, 0, stream>>>(cc, wob, bo, out);
}